// Round 8
// baseline (264.503 us; speedup 1.0000x reference)
//
#include <hip/hip_runtime.h>

#define DEVFN __device__ __forceinline__

constexpr int B  = 16;
constexpr int C  = 256;
constexpr int N  = 64 * 64;     // 4096
constexpr int O1 = C + 4;       // 260

typedef __attribute__((ext_vector_type(8)))  short bf16x8;
typedef __attribute__((ext_vector_type(4)))  short bf16x4;
typedef __attribute__((ext_vector_type(16))) float f32x16;
typedef __attribute__((ext_vector_type(2)))  _Float16 h2;
typedef unsigned short ushort_t;
typedef unsigned int   uint32;

DEVFN short f2bf(float f){
  union { float f; unsigned u; } p; p.f = f;
  unsigned r = p.u + 0x7fffu + ((p.u >> 16) & 1u);   // RNE
  return (short)(r >> 16);
}
DEVFN unsigned pack2(float lo, float hi){
  return (unsigned)(ushort_t)f2bf(lo) | ((unsigned)(ushort_t)f2bf(hi) << 16);
}
DEVFN float lo2f(unsigned u){ union{unsigned u; float f;} p; p.u = u << 16; return p.f; }
DEVFN float hi2f(unsigned u){ union{unsigned u; float f;} p; p.u = u & 0xffff0000u; return p.f; }
DEVFN float bf2f(ushort_t s){ union{unsigned u; float f;} p; p.u = (unsigned)s << 16; return p.f; }

// logistic-form gelu, log2e folded into cubic constants; exp2 neg is a free
// source modifier. max err ~5e-4.
DEVFN float gelu_fast(float x){
  float s = x * x;
  float t = x * fmaf(s, 0.1029432f, 2.3022082f);   // 1.59576912*(1+.044715x^2)*log2e
  float e = __builtin_amdgcn_exp2f(-t);
  return x * __builtin_amdgcn_rcpf(1.0f + e);
}

// fp16 pair dot with f32 accumulate (v_dot2_f32_f16).
DEVFN float fdot2f(uint32 a, uint32 b, float c){
#if __has_builtin(__builtin_amdgcn_fdot2)
  return __builtin_amdgcn_fdot2(__builtin_bit_cast(h2, a),
                                __builtin_bit_cast(h2, b), c, false);
#else
  h2 ha = __builtin_bit_cast(h2, a), hb = __builtin_bit_cast(h2, b);
  return fmaf((float)ha.x, (float)hb.x, fmaf((float)ha.y, (float)hb.y, c));
#endif
}

DEVFN uint32 pkh(float a, float b){   // pack 2 f32 -> fp16 pair (RNE)
  _Float16 ha = (_Float16)a, hb = (_Float16)b;
  return (uint32)__builtin_bit_cast(ushort_t, ha) |
         ((uint32)__builtin_bit_cast(ushort_t, hb) << 16);
}

// ---------------- K0: weight pre-convert + x transpose-to-bf16 -------------
// blocks 0..319   : conv_w -> zero-padded bf16 wbf[320][256]
// block  320      : dw weights -> fp16 pairs
// blocks 321..832 : x[b][c][n] -> xbf[b][kg][n][8]  (bf16, fragment layout,
//                   so k_conv1 can stage X via global_load_lds with NO regs)
__global__ __launch_bounds__(256)
void k_wbf(const float* __restrict__ w, ushort_t* __restrict__ wbf,
           const float* __restrict__ fw3, const float* __restrict__ fw5,
           const float* __restrict__ fw7, uint32* __restrict__ w3p,
           uint32* __restrict__ w5p, uint32* __restrict__ w7p,
           const float* __restrict__ x, ushort_t* __restrict__ xbf){
  if(blockIdx.x >= 321){
    const int blk = blockIdx.x - 321;        // 0..511 = b*32 + kg
    const int b  = blk >> 5;
    const int kg = blk & 31;
    const float* xs = x + ((size_t)(b * 256 + kg * 8)) * N;
    ushort_t* xd = xbf + ((size_t)(b * 32 + kg)) * N * 8;
    #pragma unroll
    for(int it = 0; it < 4; it++){
      const int n = (it * 256 + threadIdx.x) * 4;
      float4 cv[8];
      #pragma unroll
      for(int j = 0; j < 8; j++) cv[j] = *(const float4*)(xs + (size_t)j * N + n);
      #pragma unroll
      for(int p = 0; p < 4; p++){
        uint4 v;
        v.x = pack2(((const float*)&cv[0])[p], ((const float*)&cv[1])[p]);
        v.y = pack2(((const float*)&cv[2])[p], ((const float*)&cv[3])[p]);
        v.z = pack2(((const float*)&cv[4])[p], ((const float*)&cv[5])[p]);
        v.w = pack2(((const float*)&cv[6])[p], ((const float*)&cv[7])[p]);
        *(uint4*)(xd + (size_t)(n + p) * 8) = v;
      }
    }
    return;
  }
  if(blockIdx.x == 320){
    const int c = threadIdx.x;          // one channel per thread
    #pragma unroll
    for(int ky = 0; ky < 3; ky++){
      const float* wr = fw3 + c * 9 + ky * 3;
      w3p[c * 6 + ky * 2 + 0] = pkh(wr[0], wr[1]);
      w3p[c * 6 + ky * 2 + 1] = pkh(wr[2], 0.f);
    }
    #pragma unroll
    for(int ky = 0; ky < 5; ky++){
      const float* wr = fw5 + c * 25 + ky * 5;
      w5p[c * 15 + ky * 3 + 0] = pkh(wr[0], wr[1]);
      w5p[c * 15 + ky * 3 + 1] = pkh(wr[2], wr[3]);
      w5p[c * 15 + ky * 3 + 2] = pkh(wr[4], 0.f);
    }
    #pragma unroll
    for(int ky = 0; ky < 7; ky++){
      const float* wr = fw7 + c * 49 + ky * 7;
      w7p[c * 28 + ky * 4 + 0] = pkh(wr[0], wr[1]);
      w7p[c * 28 + ky * 4 + 1] = pkh(wr[2], wr[3]);
      w7p[c * 28 + ky * 4 + 2] = pkh(wr[4], wr[5]);
      w7p[c * 28 + ky * 4 + 3] = pkh(wr[6], 0.f);
    }
    return;
  }
  int idx = blockIdx.x * 256 + threadIdx.x;   // 320*256 = 81920
  int o = idx >> 8, cc = idx & 255;
  wbf[idx] = (o < O1) ? (ushort_t)f2bf(w[o * 256 + cc]) : (ushort_t)0;
}

// ---------------- K1: conv1x1 MFMA GEMM, single-pass-over-x ----------
// 512 thr / 8 waves. M=256 exact via MFMA (wave w owns m-tile w x 64px).
// Gate rows on the VALU pipe (waves 0-3). ALL staging is async
// global_load_lds (zero staging VGPRs). BK=32, X/W double-buffered.
// R6's __syncthreads per chunk drained vmcnt(0) -> every chunk paid the
// full DMA round trip of the JUST-ISSUED loads. Now: counted s_waitcnt
// vmcnt(3|2) (only chunk-k loads must land; chunk-k+1's stay in flight
// across a raw s_barrier) + a wait-free trailing s_barrier for the WAR
// hazard on the double buffer (T3/T4). LDS 45KB -> 3 blocks/CU.
// NEVER accumulate via dense f32 atomics (R5: 557MB HBM RMW traffic, 10x).
__global__ __launch_bounds__(512, 6)
void k_conv1_mfma(const ushort_t* __restrict__ xbf, const ushort_t* __restrict__ wbf,
                  const float* __restrict__ conv_w, const float* __restrict__ bias,
                  ushort_t* __restrict__ ctxb, float* __restrict__ gates){
  __shared__ __align__(16) short wlds[2][4 * 256 * 8];   // 2x16KB [kg][m][8]
  __shared__ __align__(16) short xlds[2][4 * 64 * 8];    // 2x 4KB [kg][n][8]
  __shared__ float sgw[4 * 256];                         //  4KB gate weights f32
  __shared__ float sbias[256];
  const int tid  = threadIdx.x;
  const int wave = tid >> 6;          // 0..7 = m-tile index
  const int lane = tid & 63;
  const int l31  = lane & 31;
  const int lhi  = lane >> 5;
  const int pg   = blockIdx.x;
  const int b    = pg >> 6;
  const int n0   = (pg & 63) * 64;

  // prologue staging: gate weights (rows 256..259 of conv_w, f32) + bias
  #pragma unroll
  for(int i = 0; i < 2; i++) sgw[i * 512 + tid] = conv_w[256 * 256 + i * 512 + tid];
  if(tid < 256) sbias[tid] = bias[tid];
  const int gidx = tid >> 6;          // gate row for waves 0..3
  const int gn   = tid & 63;
  float gbias = (tid < 256) ? bias[256 + gidx] : 0.f;
  float gacc = 0.f;

  f32x16 acc[2];
  #pragma unroll
  for(int t = 0; t < 2; t++)
    #pragma unroll
    for(int r = 0; r < 16; r++) acc[t][r] = 0.f;

  // X stage: waves 0-3, one 16B DMA per thread. Dest = tid*16 within buffer
  // (wave-uniform base + lane*16 ✓). Source = xbf fragment (16B contiguous).
  auto glX = [&](int kc, int bf){
    if(tid < 256){
      const int kg = tid >> 6, n = tid & 63;
      const ushort_t* src = xbf + ((size_t)(b * 32 + (kc >> 3) + kg) * N + n0 + n) * 8;
      __builtin_amdgcn_global_load_lds(
          (const __attribute__((address_space(1))) unsigned int*)src,
          (__attribute__((address_space(3))) unsigned int*)&xlds[bf][(size_t)tid * 8],
          16, 0, 0);
    }
  };
  // W stage: async global->LDS, 16B/lane (L2-hot, pure copy). 2 loads/thread.
  auto glW = [&](int kc, int bf){
    #pragma unroll
    for(int q = 0; q < 2; q++){
      const int pidx = q * 512 + tid;        // 0..1023 = kg*256+m
      const int kg = pidx >> 8;
      const int m  = pidx & 255;
      const ushort_t* src = wbf + (size_t)m * 256 + kc + kg * 8;
      __builtin_amdgcn_global_load_lds(
          (const __attribute__((address_space(1))) unsigned int*)src,
          (__attribute__((address_space(3))) unsigned int*)&wlds[bf][(size_t)pidx * 8],
          16, 0, 0);
    }
  };
  auto mfmaC = [&](int bf){
    #pragma unroll
    for(int ks = 0; ks < 2; ks++){
      const int kg = ks * 2 + lhi;
      bf16x8 af = *(const bf16x8*)&wlds[bf][(kg * 256 + wave * 32 + l31) * 8];
      bf16x8 b0 = *(const bf16x8*)&xlds[bf][(kg * 64 + l31) * 8];
      bf16x8 b1 = *(const bf16x8*)&xlds[bf][(kg * 64 + 32 + l31) * 8];
      acc[0] = __builtin_amdgcn_mfma_f32_32x32x16_bf16(af, b0, acc[0], 0, 0, 0);
      acc[1] = __builtin_amdgcn_mfma_f32_32x32x16_bf16(af, b1, acc[1], 0, 0, 0);
    }
  };
  auto gateC = [&](int bf, int kc){
    if(tid < 256){
      float a = gacc;
      #pragma unroll
      for(int kg = 0; kg < 4; kg++){
        bf16x8 xv = *(const bf16x8*)&xlds[bf][(kg * 64 + gn) * 8];
        const float* gw = &sgw[gidx * 256 + kc + kg * 8];
        #pragma unroll
        for(int j = 0; j < 4; j++){
          unsigned u = ((const unsigned*)&xv)[j];
          a = fmaf(lo2f(u), gw[2 * j], a);
          a = fmaf(hi2f(u), gw[2 * j + 1], a);
        }
      }
      gacc = a;
    }
  };

  // prologue: stage chunk 0 into buffer 0; ONE full drain (also publishes
  // the sgw/sbias LDS writes to all waves).
  glX(0, 0); glW(0, 0);
  __syncthreads();
  // steady chunks: issue next DMA; counted wait (chunk-c loads only);
  // raw barrier; compute; wait-free barrier (WAR on the write target).
  #pragma unroll
  for(int c = 0; c < 7; c++){
    const int bf = c & 1;
    glX((c + 1) * 32, bf ^ 1);
    glW((c + 1) * 32, bf ^ 1);
    if(wave < 4) asm volatile("s_waitcnt vmcnt(3)" ::: "memory");
    else         asm volatile("s_waitcnt vmcnt(2)" ::: "memory");
    __builtin_amdgcn_s_barrier();
    __builtin_amdgcn_sched_barrier(0);
    mfmaC(bf);
    gateC(bf, c * 32);
    __builtin_amdgcn_s_barrier();   // all ds_read results already consumed
                                    // (lgkm drained by MFMA/FMA uses)
  }
  // last chunk (7): everything issued; drain remaining loads, compute.
  asm volatile("s_waitcnt vmcnt(0)" ::: "memory");
  __builtin_amdgcn_s_barrier();
  __builtin_amdgcn_sched_barrier(0);
  mfmaC(1);
  gateC(1, 224);

  // epilogue ctx: C/D layout col=lane&31, row=(r&3)+8*(r>>2)+4*lhi; all o<256
  #pragma unroll
  for(int nt = 0; nt < 2; nt++){
    const int n = n0 + nt * 32 + l31;
    #pragma unroll
    for(int r = 0; r < 16; r++){
      const int row = (r & 3) + 8 * (r >> 2) + 4 * lhi;
      const int o = wave * 32 + row;
      const float v = acc[nt][r] + sbias[o];
      _Float16 hv = (_Float16)v;                 // fp16 chain input
      ctxb[((size_t)(b * 256 + o)) * N + n] = __builtin_bit_cast(ushort_t, hv);
    }
  }
  // epilogue gates (waves 0..3)
  if(tid < 256)
    gates[((size_t)(b * 4 + gidx)) * N + n0 + gn] = gacc + gbias;
}

// ---------------- fused depthwise chain: fp16 pairs + v_dot2_f32_f16 --------
// NOTE: row stride 72 shorts = 36 dwords == 4 (mod 32 banks) -> benign for
// b128 reads (8 lanes per 4-bank group); layout identical to bf16 version.
constexpr int SSTR = 72;

// Horizontal conv via packed pairs: P[j] = fp16 pair (rel col 2j, 2j+1),
// S[j] = shifted pair (2j+1, 2j+2) built with one v_alignbit_b32.
template<int K>
DEVFN void dw_stage_dot(const short* src, const uint32* __restrict__ wp,
                        int h, int w0, float* val){
  constexpr int R = K / 2;
  constexpr int PAIRS = (K + 2) / 2;   // 3->2, 5->3, 7->4
  float acc[8];
  #pragma unroll
  for(int i = 0; i < 8; i++) acc[i] = 0.f;
  #pragma unroll
  for(int ky = 0; ky < K; ky++){
    uint32 wk[PAIRS];                   // uniform -> scalar loads
    #pragma unroll
    for(int t = 0; t < PAIRS; t++) wk[t] = wp[ky * PAIRS + t];
    const int r = h + ky - R;
    if((unsigned)r < 64u){
      const short* rp = &src[r * SSTR + w0];
      uint4 a0 = *(const uint4*)rp;
      uint4 a1 = *(const uint4*)(rp + 8);
      uint32 P[8] = {a0.x, a0.y, a0.z, a0.w, a1.x, a1.y, a1.z, a1.w};
      uint32 S[7];
      #pragma unroll
      for(int j = 0; j < 7; j++)
        S[j] = __builtin_amdgcn_alignbit(P[j + 1], P[j], 16);  // unused DCE'd
      #pragma unroll
      for(int i = 0; i < 8; i++){
        int j0, useP;
        if      (K == 7){ useP =  (i & 1); j0 = (i + 1) >> 1; }
        else if (K == 5){ useP = !(i & 1); j0 = (i >> 1) + 1; }
        else            { useP =  (i & 1); j0 = (i >> 1) + ((i & 1) ? 2 : 1); }
        #pragma unroll
        for(int t = 0; t < PAIRS; t++){
          const uint32 a = useP ? P[j0 + t] : S[j0 + t];
          acc[i] = fdot2f(a, wk[t], acc[i]);
        }
      }
    }
  }
  #pragma unroll
  for(int i = 0; i < 8; i++) val[i] = gelu_fast(acc[i]);
}

DEVFN void store_row_h(short* dst, int h, int w0, const float* val){
  uint32 o0 = __builtin_bit_cast(uint32, __builtin_amdgcn_cvt_pkrtz(val[0], val[1]));
  uint32 o1 = __builtin_bit_cast(uint32, __builtin_amdgcn_cvt_pkrtz(val[2], val[3]));
  uint32 o2 = __builtin_bit_cast(uint32, __builtin_amdgcn_cvt_pkrtz(val[4], val[5]));
  uint32 o3 = __builtin_bit_cast(uint32, __builtin_amdgcn_cvt_pkrtz(val[6], val[7]));
  uint2 t0; t0.x = o0; t0.y = o1;
  uint2 t1; t1.x = o2; t1.y = o3;
  *(uint2*)&dst[h * SSTR + w0 + 4] = t0;
  *(uint2*)&dst[h * SSTR + w0 + 8] = t1;
}

__global__ __launch_bounds__(512, 8)
void k_dwchain(ushort_t* __restrict__ ctxb, const uint32* __restrict__ w3p,
               const uint32* __restrict__ w5p, const uint32* __restrict__ w7p,
               const float* __restrict__ gates){
  __shared__ __align__(16) short bufA[64 * SSTR];
  __shared__ __align__(16) short bufB[64 * SSTR];
  __shared__ float wred[8];
  const int tid = threadIdx.x;
  const int plane = blockIdx.x;
  const int b = plane >> 8;
  const int c = plane & 255;
  const int h  = tid >> 3;
  const int w0 = (tid & 7) * 8;
  const int nbase = h * 64 + w0;

  if(tid < 64){
    bf16x4 z = {0, 0, 0, 0};
    *(bf16x4*)&bufA[tid * SSTR] = z;  *(bf16x4*)&bufA[tid * SSTR + 68] = z;
    *(bf16x4*)&bufB[tid * SSTR] = z;  *(bf16x4*)&bufB[tid * SSTR + 68] = z;
  }
  {
    // ctxb holds fp16 from conv1: straight bit-copy into LDS (no convert)
    const uint4 iv = *(const uint4*)((const short*)ctxb + (size_t)plane * N + tid * 8);
    uint2 t0; t0.x = iv.x; t0.y = iv.y;
    uint2 t1; t1.x = iv.z; t1.y = iv.w;
    *(uint2*)&bufA[h * SSTR + w0 + 4] = t0;
    *(uint2*)&bufA[h * SSTR + w0 + 8] = t1;
  }
  __syncthreads();

  float ctxp[8];
  #pragma unroll
  for(int i = 0; i < 8; i++) ctxp[i] = 0.f;
  float val[8];

  // stage 1: dw3 A->B
  dw_stage_dot<3>(bufA, w3p + c * 6, h, w0, val);
  {
    const float* gp = gates + ((size_t)(b * 4 + 0)) * N + nbase;
    float4 ga = *(const float4*)gp, gb = *(const float4*)(gp + 4);
    ctxp[0] = fmaf(val[0], ga.x, ctxp[0]); ctxp[1] = fmaf(val[1], ga.y, ctxp[1]);
    ctxp[2] = fmaf(val[2], ga.z, ctxp[2]); ctxp[3] = fmaf(val[3], ga.w, ctxp[3]);
    ctxp[4] = fmaf(val[4], gb.x, ctxp[4]); ctxp[5] = fmaf(val[5], gb.y, ctxp[5]);
    ctxp[6] = fmaf(val[6], gb.z, ctxp[6]); ctxp[7] = fmaf(val[7], gb.w, ctxp[7]);
    store_row_h(bufB, h, w0, val);
  }
  __syncthreads();

  // stage 2: dw5 B->A
  dw_stage_dot<5>(bufB, w5p + c * 15, h, w0, val);
  {
    const float* gp = gates + ((size_t)(b * 4 + 1)) * N + nbase;
    float4 ga = *(const float4*)gp, gb = *(const float4*)(gp + 4);
    ctxp[0] = fmaf(val[0], ga.x, ctxp[0]); ctxp[1] = fmaf(val[1], ga.y, ctxp[1]);
    ctxp[2] = fmaf(val[2], ga.z, ctxp[2]); ctxp[3] = fmaf(val[3], ga.w, ctxp[3]);
    ctxp[4] = fmaf(val[4], gb.x, ctxp[4]); ctxp[5] = fmaf(val[5], gb.y, ctxp[5]);
    ctxp[6] = fmaf(val[6], gb.z, ctxp[6]); ctxp[7] = fmaf(val[7], gb.w, ctxp[7]);
    store_row_h(bufA, h, w0, val);
  }
  __syncthreads();

  // stage 3: dw7 A->regs; plane mean of gelu output
  dw_stage_dot<7>(bufA, w7p + c * 28, h, w0, val);
  float lsum = 0.f;
  {
    const float* gp = gates + ((size_t)(b * 4 + 2)) * N + nbase;
    float4 ga = *(const float4*)gp, gb = *(const float4*)(gp + 4);
    ctxp[0] = fmaf(val[0], ga.x, ctxp[0]); ctxp[1] = fmaf(val[1], ga.y, ctxp[1]);
    ctxp[2] = fmaf(val[2], ga.z, ctxp[2]); ctxp[3] = fmaf(val[3], ga.w, ctxp[3]);
    ctxp[4] = fmaf(val[4], gb.x, ctxp[4]); ctxp[5] = fmaf(val[5], gb.y, ctxp[5]);
    ctxp[6] = fmaf(val[6], gb.z, ctxp[6]); ctxp[7] = fmaf(val[7], gb.w, ctxp[7]);
    #pragma unroll
    for(int i = 0; i < 8; i++) lsum += val[i];
  }
  #pragma unroll
  for(int off = 32; off > 0; off >>= 1) lsum += __shfl_xor(lsum, off, 64);
  if((tid & 63) == 0) wred[tid >> 6] = lsum;
  __syncthreads();
  float mean = 0.f;
  #pragma unroll
  for(int i = 0; i < 8; i++) mean += wred[i];
  mean *= (1.0f / 4096.0f);

  // ctx_all = ctxp + mean*g3 -> bf16, in place (downstream reads bf16)
  {
    const float* gp = gates + ((size_t)(b * 4 + 3)) * N + nbase;
    float4 ga = *(const float4*)gp, gb = *(const float4*)(gp + 4);
    bf16x8 ov;
    ov[0] = f2bf(fmaf(mean, ga.x, ctxp[0])); ov[1] = f2bf(fmaf(mean, ga.y, ctxp[1]));
    ov[2] = f2bf(fmaf(mean, ga.z, ctxp[2])); ov[3] = f2bf(fmaf(mean, ga.w, ctxp[3]));
    ov[4] = f2bf(fmaf(mean, gb.x, ctxp[4])); ov[5] = f2bf(fmaf(mean, gb.y, ctxp[5]));
    ov[6] = f2bf(fmaf(mean, gb.z, ctxp[6])); ov[7] = f2bf(fmaf(mean, gb.w, ctxp[7]));
    *(bf16x8*)((short*)ctxb + (size_t)plane * N + nbase) = ov;
  }
}

// ---------------- logits[b,n] = sum_c kw[c]*ctxall[b,c,n] + kb (bf16 read) ----
__global__ __launch_bounds__(256)
void k_logits(const ushort_t* __restrict__ P, const float* __restrict__ key_w,
              const float* __restrict__ key_b, float* __restrict__ logits){
  __shared__ float kw[256];
  __shared__ float part[512];
  int tid = threadIdx.x;
  kw[tid] = key_w[tid];
  __syncthreads();
  int b  = blockIdx.x >> 5;
  int n0 = (blockIdx.x & 31) * 128;
  int cpart = tid >> 6, pxp = tid & 63;
  const ushort_t* pp = P + ((size_t)(b * 256 + cpart * 64)) * N + n0 + pxp * 2;
  float a0 = 0.f, a1 = 0.f;
  #pragma unroll 8
  for(int c = 0; c < 64; c++){
    unsigned u = *(const unsigned*)(pp + (size_t)c * N);
    float kwv = kw[cpart * 64 + c];
    a0 = fmaf(lo2f(u), kwv, a0);
    a1 = fmaf(hi2f(u), kwv, a1);
  }
  part[cpart * 128 + pxp * 2]     = a0;
  part[cpart * 128 + pxp * 2 + 1] = a1;
  __syncthreads();
  if(tid < 128){
    float l = part[tid] + part[128 + tid] + part[256 + tid] + part[384 + tid];
    logits[b * N + n0 + tid] = l + key_b[0];
  }
}

// ---------------- qk with integrated softmax (reads RAW logits) ------------
__global__ __launch_bounds__(256)
void k_qk(const ushort_t* __restrict__ P, const float* __restrict__ logits,
          float* __restrict__ qk){
  __shared__ float red[256];
  __shared__ float wred[4];
  const int plane = blockIdx.x, tid = threadIdx.x;
  const int b = plane >> 8;
  const int wave = tid >> 6, lane = tid & 63;
  const float2* lp = (const float2*)(logits + b * N);
  float2 l2[8];
  float m = -1e30f;
  #pragma unroll
  for(int i = 0; i < 8; i++){
    l2[i] = lp[tid + i * 256];
    m = fmaxf(m, fmaxf(l2[i].x, l2[i].y));
  }
  #pragma unroll
  for(int off = 32; off > 0; off >>= 1) m = fmaxf(m, __shfl_xor(m, off, 64));
  if(lane == 0) wred[wave] = m;
  __syncthreads();
  m = fmaxf(fmaxf(wred[0], wred[1]), fmaxf(wred[2], wred[3]));
  __syncthreads();
  float s = 0.f;
  #pragma unroll
  for(int i = 0; i < 8; i++){
    l2[i].x = __expf(l2[i].x - m);
    l2[i].y = __expf(l2[i].y - m);
    s += l2[i].x + l2[i].y;
  }
  #pragma unroll
  for(int off = 32; off > 0; off >>= 1) s += __shfl_xor(s, off, 64);
  if(lane == 0) wred[wave] = s;
  __syncthreads();
  const float stot = wred[0] + wred[1] + wred[2] + wred[3];
  const unsigned* pp = (const unsigned*)(P + (size_t)plane * N);
  float acc = 0.f;
  #pragma unroll
  for(int i = 0; i < 8; i++){
    unsigned u = pp[tid + i * 256];
    acc = fmaf(lo2f(u), l2[i].x, acc);
    acc = fmaf(hi2f(u), l2[i].y, acc);
  }
  red[tid] = acc; __syncthreads();
  for(int t = 128; t > 0; t >>= 1){
    if(tid < t) red[tid] += red[tid + t];
    __syncthreads();
  }
  if(tid == 0) qk[plane] = red[0] / stot;
}

// ---------------- final: out = f32(ctx_all) + v, v recomputed in-block -----
__global__ __launch_bounds__(256)
void k_final(float* __restrict__ out, const ushort_t* __restrict__ ctxb,
             const float* __restrict__ qkb, const float* __restrict__ v1w,
             const float* __restrict__ v1b, const float* __restrict__ lnw,
             const float* __restrict__ lnb, const float* __restrict__ v2w,
             const float* __restrict__ v2b){
  __shared__ float part[256];
  __shared__ float v1s[16];
  __shared__ float bc[1];
  const int tid  = threadIdx.x;
  const int idx8 = blockIdx.x * 256 + tid;
  const int plane = idx8 >> 9;               // uniform within block
  const int b = plane >> 8, c = plane & 255;
  const int oc = tid >> 4, ln = tid & 15;
  const float* qs = qkb + b * 256;           // 1KB, L2-hot
  float p = 0.f;
  #pragma unroll
  for(int j = 0; j < 16; j++){
    const int cc = ln + j * 16;
    p = fmaf(v1w[oc * 256 + cc], qs[cc], p);
  }
  part[tid] = p;
  __syncthreads();
  if(tid < 16){
    float s = v1b[tid];
    #pragma unroll
    for(int j = 0; j < 16; j++) s += part[tid * 16 + j];
    v1s[tid] = s;
  }
  __syncthreads();
  if(tid == 0){
    float mu = 0.f;
    #pragma unroll
    for(int i = 0; i < 16; i++) mu += v1s[i];
    mu *= (1.f / 16.f);
    float var = 0.f;
    #pragma unroll
    for(int i = 0; i < 16; i++){ float d = v1s[i] - mu; var += d * d; }
    var *= (1.f / 16.f);
    const float rs = rsqrtf(var + 1e-5f);
    float o = v2b[c];
    #pragma unroll
    for(int i = 0; i < 16; i++){
      float vv = (v1s[i] - mu) * rs * lnw[i] + lnb[i];
      o = fmaf(v2w[c * 16 + i], fmaxf(vv, 0.f), o);
    }
    bc[0] = o;
  }
  __syncthreads();
  const float vv = bc[0];
  const int off = (idx8 & 511) * 8;
  bf16x8 v = *(const bf16x8*)((const short*)ctxb + (size_t)plane * N + off);
  float4 o0, o1;
  o0.x = bf2f((ushort_t)v[0]) + vv; o0.y = bf2f((ushort_t)v[1]) + vv;
  o0.z = bf2f((ushort_t)v[2]) + vv; o0.w = bf2f((ushort_t)v[3]) + vv;
  o1.x = bf2f((ushort_t)v[4]) + vv; o1.y = bf2f((ushort_t)v[5]) + vv;
  o1.z = bf2f((ushort_t)v[6]) + vv; o1.w = bf2f((ushort_t)v[7]) + vv;
  float* op = out + (size_t)plane * N + off;
  *(float4*)op = o0;
  *(float4*)(op + 4) = o1;
}

extern "C" void kernel_launch(void* const* d_in, const int* in_sizes, int n_in,
                              void* d_out, int out_size, void* d_ws, size_t ws_size,
                              hipStream_t stream){
  const float* x      = (const float*)d_in[0];
  const float* conv_w = (const float*)d_in[1];
  const float* conv_b = (const float*)d_in[2];
  const float* fw3    = (const float*)d_in[3];
  const float* fw5    = (const float*)d_in[4];
  const float* fw7    = (const float*)d_in[5];
  const float* key_w  = (const float*)d_in[6];
  const float* key_b  = (const float*)d_in[7];
  const float* v1_w   = (const float*)d_in[8];
  const float* v1_b   = (const float*)d_in[9];
  const float* ln_w   = (const float*)d_in[10];
  const float* ln_b   = (const float*)d_in[11];
  const float* v2_w   = (const float*)d_in[12];
  const float* v2_b   = (const float*)d_in[13];
  float* out = (float*)d_out;

  const size_t PL = (size_t)B * C * N;     // 16,777,216 elements
  char* p = (char*)d_ws;
  ushort_t* ctxb = (ushort_t*)p;  p += PL * sizeof(ushort_t);          // 32 MB
  float* gates   = (float*)p;     p += (size_t)B * 4 * N * sizeof(float);
  float* kbuf    = (float*)p;     p += (size_t)B * N * sizeof(float);
  float* qkb     = (float*)p;     p += (size_t)B * C * sizeof(float);
  ushort_t* wbf  = (ushort_t*)p;  p += (size_t)320 * 256 * sizeof(ushort_t);
  uint32* w3p    = (uint32*)p;    p += (size_t)256 * 6 * sizeof(uint32);
  uint32* w5p    = (uint32*)p;    p += (size_t)256 * 15 * sizeof(uint32);
  uint32* w7p    = (uint32*)p;
  // xbf (32MB) lives in d_out: nothing reads out until k_final overwrites it,
  // and xbf's last reader (k_conv1) precedes k_final on the same stream.
  ushort_t* xbf  = (ushort_t*)d_out;

  // 0. weight pre-convert + x transpose to bf16 fragment layout
  k_wbf<<<833, 256, 0, stream>>>(conv_w, wbf, fw3, fw5, fw7, w3p, w5p, w7p,
                                 x, xbf);
  // 1. conv1x1 via bf16 MFMA, counted-vmcnt pipelined staging
  k_conv1_mfma<<<1024, 512, 0, stream>>>(xbf, wbf, conv_w, conv_b, ctxb, gates);
  // 2. fused dw3/dw5/dw7 chain (fp16 + v_dot2) -> ctxb overwritten bf16 ctx_all
  k_dwchain<<<B * C, 512, 0, stream>>>(ctxb, w3p, w5p, w7p, gates);
  // 3. raw logits (reads bf16 ctx_all)
  k_logits<<<512, 256, 0, stream>>>(ctxb, key_w, key_b, kbuf);
  // 4. qk with integrated per-block softmax (reads raw logits)
  k_qk<<<B * C, 256, 0, stream>>>(ctxb, kbuf, qkb);
  // 5. final: out = f32(ctx_all) + v recomputed in-block from qkb
  k_final<<<8192, 256, 0, stream>>>(out, ctxb, qkb, v1_w, v1_b, ln_w, ln_b,
                                    v2_w, v2_b);
}

// Round 9
// 250.081 us; speedup vs baseline: 1.0577x; 1.0577x over previous
//
#include <hip/hip_runtime.h>

#define DEVFN __device__ __forceinline__

constexpr int B  = 16;
constexpr int C  = 256;
constexpr int N  = 64 * 64;     // 4096
constexpr int O1 = C + 4;       // 260

typedef __attribute__((ext_vector_type(8)))  short bf16x8;
typedef __attribute__((ext_vector_type(4)))  short bf16x4;
typedef __attribute__((ext_vector_type(16))) float f32x16;
typedef __attribute__((ext_vector_type(2)))  _Float16 h2;
typedef unsigned short ushort_t;
typedef unsigned int   uint32;

DEVFN short f2bf(float f){
  union { float f; unsigned u; } p; p.f = f;
  unsigned r = p.u + 0x7fffu + ((p.u >> 16) & 1u);   // RNE
  return (short)(r >> 16);
}
DEVFN unsigned pack2(float lo, float hi){
  return (unsigned)(ushort_t)f2bf(lo) | ((unsigned)(ushort_t)f2bf(hi) << 16);
}
DEVFN float lo2f(unsigned u){ union{unsigned u; float f;} p; p.u = u << 16; return p.f; }
DEVFN float hi2f(unsigned u){ union{unsigned u; float f;} p; p.u = u & 0xffff0000u; return p.f; }
DEVFN float bf2f(ushort_t s){ union{unsigned u; float f;} p; p.u = (unsigned)s << 16; return p.f; }

// logistic-form gelu, log2e folded into cubic constants; exp2 neg is a free
// source modifier. max err ~5e-4.
DEVFN float gelu_fast(float x){
  float s = x * x;
  float t = x * fmaf(s, 0.1029432f, 2.3022082f);   // 1.59576912*(1+.044715x^2)*log2e
  float e = __builtin_amdgcn_exp2f(-t);
  return x * __builtin_amdgcn_rcpf(1.0f + e);
}

// fp16 pair dot with f32 accumulate (v_dot2_f32_f16).
DEVFN float fdot2f(uint32 a, uint32 b, float c){
#if __has_builtin(__builtin_amdgcn_fdot2)
  return __builtin_amdgcn_fdot2(__builtin_bit_cast(h2, a),
                                __builtin_bit_cast(h2, b), c, false);
#else
  h2 ha = __builtin_bit_cast(h2, a), hb = __builtin_bit_cast(h2, b);
  return fmaf((float)ha.x, (float)hb.x, fmaf((float)ha.y, (float)hb.y, c));
#endif
}

DEVFN uint32 pkh(float a, float b){   // pack 2 f32 -> fp16 pair (RNE)
  _Float16 ha = (_Float16)a, hb = (_Float16)b;
  return (uint32)__builtin_bit_cast(ushort_t, ha) |
         ((uint32)__builtin_bit_cast(ushort_t, hb) << 16);
}

// ---------------- K0: weight pre-convert (NO x pass anymore) ---------------
// blocks 0..319 : conv_w -> zero-padded bf16 wbf[320][256]
// block  320    : dw weights -> fp16 pairs
// The x transpose pass (96MB stream, ~15-25us) is deleted: conv1 now stages
// X as f32 via global_load_lds and repacks to bf16 inside its own LDS.
__global__ __launch_bounds__(256)
void k_wbf(const float* __restrict__ w, ushort_t* __restrict__ wbf,
           const float* __restrict__ fw3, const float* __restrict__ fw5,
           const float* __restrict__ fw7, uint32* __restrict__ w3p,
           uint32* __restrict__ w5p, uint32* __restrict__ w7p){
  if(blockIdx.x == 320){
    const int c = threadIdx.x;          // one channel per thread
    #pragma unroll
    for(int ky = 0; ky < 3; ky++){
      const float* wr = fw3 + c * 9 + ky * 3;
      w3p[c * 6 + ky * 2 + 0] = pkh(wr[0], wr[1]);
      w3p[c * 6 + ky * 2 + 1] = pkh(wr[2], 0.f);
    }
    #pragma unroll
    for(int ky = 0; ky < 5; ky++){
      const float* wr = fw5 + c * 25 + ky * 5;
      w5p[c * 15 + ky * 3 + 0] = pkh(wr[0], wr[1]);
      w5p[c * 15 + ky * 3 + 1] = pkh(wr[2], wr[3]);
      w5p[c * 15 + ky * 3 + 2] = pkh(wr[4], 0.f);
    }
    #pragma unroll
    for(int ky = 0; ky < 7; ky++){
      const float* wr = fw7 + c * 49 + ky * 7;
      w7p[c * 28 + ky * 4 + 0] = pkh(wr[0], wr[1]);
      w7p[c * 28 + ky * 4 + 1] = pkh(wr[2], wr[3]);
      w7p[c * 28 + ky * 4 + 2] = pkh(wr[4], wr[5]);
      w7p[c * 28 + ky * 4 + 3] = pkh(wr[6], 0.f);
    }
    return;
  }
  int idx = blockIdx.x * 256 + threadIdx.x;   // 320*256 = 81920
  int o = idx >> 8, cc = idx & 255;
  wbf[idx] = (o < O1) ? (ushort_t)f2bf(w[o * 256 + cc]) : (ushort_t)0;
}

// ---------------- K1: conv1x1 MFMA GEMM, single-pass-over-x ----------
// 512 thr / 8 waves. M=256 exact via MFMA (wave w owns m-tile w x 64px).
// Gate rows on the VALU pipe (waves 0-3). ALL staging async global_load_lds
// (zero staging VGPRs -- R1/R3 reg-prefetch spilled). X is staged as f32
// (one 16B DMA/thread into xf32[2], [k][n] layout) and repacked to the bf16
// fragment layout in a ~8-VALU phase between the two existing barriers --
// this replaces the k_wbf global transpose pass. W single-buffered 16KB
// (L2-hot, R4-proven between-barriers). LDS 45KB -> 3 blocks/CU.
// Plain __syncthreads (R8's counted-vmcnt experiment was -4us: reverted).
// NEVER accumulate via dense f32 atomics (R5: 557MB HBM RMW traffic, 10x).
__global__ __launch_bounds__(512, 6)
void k_conv1_mfma(const float* __restrict__ x, const ushort_t* __restrict__ wbf,
                  const float* __restrict__ conv_w, const float* __restrict__ bias,
                  ushort_t* __restrict__ ctxb, float* __restrict__ gates){
  __shared__ __align__(16) short wlds[4 * 256 * 8];      // 16KB [kg][m][8]
  __shared__ __align__(16) float xf32[2][32 * 64];       // 2x8KB [k][n] f32
  __shared__ __align__(16) short xlds[2][4 * 64 * 8];    // 2x4KB [kg][n][8]
  __shared__ float sgw[4 * 256];                         //  4KB gate weights
  __shared__ float sbias[256];
  const int tid  = threadIdx.x;
  const int wave = tid >> 6;          // 0..7 = m-tile index
  const int lane = tid & 63;
  const int l31  = lane & 31;
  const int lhi  = lane >> 5;
  const int pg   = blockIdx.x;
  const int b    = pg >> 6;
  const int n0   = (pg & 63) * 64;

  const float* xpb = x + (size_t)b * C * N + n0;

  // X stage: one 16B f32 DMA per thread. Dest = tid*16 (wave-uniform base +
  // lane*16 ✓). Source = 4 consecutive n of row (kc+kg) -- 16B contiguous.
  auto glXf32 = [&](int kc, int bf){
    const int kg = tid >> 4, nq = tid & 15;     // [32 k][16 quads]
    const float* src = xpb + (size_t)(kc + kg) * N + nq * 4;
    __builtin_amdgcn_global_load_lds(
        (const __attribute__((address_space(1))) unsigned int*)src,
        (__attribute__((address_space(3))) unsigned int*)&xf32[bf][(size_t)tid * 4],
        16, 0, 0);
  };
  // W stage: async global->LDS, 16B/lane (L2-hot). Single buffer.
  auto glW = [&](int kc){
    #pragma unroll
    for(int q = 0; q < 2; q++){
      const int pidx = q * 512 + tid;        // 0..1023 = kg*256+m
      const int kg = pidx >> 8;
      const int m  = pidx & 255;
      const ushort_t* src = wbf + (size_t)m * 256 + kc + kg * 8;
      __builtin_amdgcn_global_load_lds(
          (const __attribute__((address_space(1))) unsigned int*)src,
          (__attribute__((address_space(3))) unsigned int*)&wlds[(size_t)pidx * 8],
          16, 0, 0);
    }
  };
  // Repack xf32[bf] ([k][n] f32) -> xlds[bf] ([kg][n][8] bf16).
  // thread -> (kgrp 0..3, n 0..63, half 0..1); reads 4 f32 at stride 64
  // (2-way bank alias = free), writes one b64. ~8 VALU.
  auto repack = [&](int bf){
    const int half = tid & 1, n = (tid >> 1) & 63, kgrp = tid >> 7;
    const float* s = &xf32[bf][(kgrp * 8 + half * 4) * 64 + n];
    bf16x4 v;
    v[0] = f2bf(s[0]);   v[1] = f2bf(s[64]);
    v[2] = f2bf(s[128]); v[3] = f2bf(s[192]);
    *(bf16x4*)&xlds[bf][(kgrp * 64 + n) * 8 + half * 4] = v;
  };
  auto mfmaC = [&](int bf, f32x16* acc){
    #pragma unroll
    for(int ks = 0; ks < 2; ks++){
      const int kg = ks * 2 + lhi;
      bf16x8 af = *(const bf16x8*)&wlds[(kg * 256 + wave * 32 + l31) * 8];
      bf16x8 b0 = *(const bf16x8*)&xlds[bf][(kg * 64 + l31) * 8];
      bf16x8 b1 = *(const bf16x8*)&xlds[bf][(kg * 64 + 32 + l31) * 8];
      acc[0] = __builtin_amdgcn_mfma_f32_32x32x16_bf16(af, b0, acc[0], 0, 0, 0);
      acc[1] = __builtin_amdgcn_mfma_f32_32x32x16_bf16(af, b1, acc[1], 0, 0, 0);
    }
  };

  // prologue staging: DMAs first (latency overlaps sgw/sbias loads)
  glXf32(0, 0); glW(0);
  #pragma unroll
  for(int i = 0; i < 2; i++) sgw[i * 512 + tid] = conv_w[256 * 256 + i * 512 + tid];
  if(tid < 256) sbias[tid] = bias[tid];
  const int gidx = tid >> 6;          // gate row for waves 0..3
  const int gn   = tid & 63;
  float gbias = (tid < 256) ? bias[256 + gidx] : 0.f;
  float gacc = 0.f;

  f32x16 acc[2];
  #pragma unroll
  for(int t = 0; t < 2; t++)
    #pragma unroll
    for(int r = 0; r < 16; r++) acc[t][r] = 0.f;

  auto gateC = [&](int bf, int kc){
    if(tid < 256){
      float a = gacc;
      #pragma unroll
      for(int kg = 0; kg < 4; kg++){
        bf16x8 xv = *(const bf16x8*)&xlds[bf][(kg * 64 + gn) * 8];
        const float* gw = &sgw[gidx * 256 + kc + kg * 8];
        #pragma unroll
        for(int j = 0; j < 4; j++){
          unsigned u = ((const unsigned*)&xv)[j];
          a = fmaf(lo2f(u), gw[2 * j], a);
          a = fmaf(hi2f(u), gw[2 * j + 1], a);
        }
      }
      gacc = a;
    }
  };

  __syncthreads();               // chunk-0 DMAs landed; sgw/sbias published
  repack(0);
  __syncthreads();
  // steady chunks: issue next X DMA; compute current; sync (drains DMA,
  // hidden under compute); W load + repack for next; sync.
  #pragma unroll
  for(int c = 0; c < 7; c++){
    const int bf = c & 1;
    glXf32((c + 1) * 32, bf ^ 1);
    mfmaC(bf, acc);
    gateC(bf, c * 32);
    __syncthreads();
    glW((c + 1) * 32);           // W read for chunk c done; safe to overwrite
    repack(bf ^ 1);
    __syncthreads();             // drains glW + publishes repack
  }
  // last chunk (7, buffer 1)
  mfmaC(1, acc);
  gateC(1, 224);

  // epilogue ctx: C/D layout col=lane&31, row=(r&3)+8*(r>>2)+4*lhi; all o<256
  #pragma unroll
  for(int nt = 0; nt < 2; nt++){
    const int n = n0 + nt * 32 + l31;
    #pragma unroll
    for(int r = 0; r < 16; r++){
      const int row = (r & 3) + 8 * (r >> 2) + 4 * lhi;
      const int o = wave * 32 + row;
      const float v = acc[nt][r] + sbias[o];
      _Float16 hv = (_Float16)v;                 // fp16 chain input
      ctxb[((size_t)(b * 256 + o)) * N + n] = __builtin_bit_cast(ushort_t, hv);
    }
  }
  // epilogue gates (waves 0..3)
  if(tid < 256)
    gates[((size_t)(b * 4 + gidx)) * N + n0 + gn] = gacc + gbias;
}

// ---------------- fused depthwise chain: fp16 pairs + v_dot2_f32_f16 --------
// NOTE: row stride 72 shorts = 36 dwords == 4 (mod 32 banks) -> benign for
// b128 reads (8 lanes per 4-bank group); layout identical to bf16 version.
constexpr int SSTR = 72;

// Horizontal conv via packed pairs: P[j] = fp16 pair (rel col 2j, 2j+1),
// S[j] = shifted pair (2j+1, 2j+2) built with one v_alignbit_b32.
template<int K>
DEVFN void dw_stage_dot(const short* src, const uint32* __restrict__ wp,
                        int h, int w0, float* val){
  constexpr int R = K / 2;
  constexpr int PAIRS = (K + 2) / 2;   // 3->2, 5->3, 7->4
  float acc[8];
  #pragma unroll
  for(int i = 0; i < 8; i++) acc[i] = 0.f;
  #pragma unroll
  for(int ky = 0; ky < K; ky++){
    uint32 wk[PAIRS];                   // uniform -> scalar loads
    #pragma unroll
    for(int t = 0; t < PAIRS; t++) wk[t] = wp[ky * PAIRS + t];
    const int r = h + ky - R;
    if((unsigned)r < 64u){
      const short* rp = &src[r * SSTR + w0];
      uint4 a0 = *(const uint4*)rp;
      uint4 a1 = *(const uint4*)(rp + 8);
      uint32 P[8] = {a0.x, a0.y, a0.z, a0.w, a1.x, a1.y, a1.z, a1.w};
      uint32 S[7];
      #pragma unroll
      for(int j = 0; j < 7; j++)
        S[j] = __builtin_amdgcn_alignbit(P[j + 1], P[j], 16);  // unused DCE'd
      #pragma unroll
      for(int i = 0; i < 8; i++){
        int j0, useP;
        if      (K == 7){ useP =  (i & 1); j0 = (i + 1) >> 1; }
        else if (K == 5){ useP = !(i & 1); j0 = (i >> 1) + 1; }
        else            { useP =  (i & 1); j0 = (i >> 1) + ((i & 1) ? 2 : 1); }
        #pragma unroll
        for(int t = 0; t < PAIRS; t++){
          const uint32 a = useP ? P[j0 + t] : S[j0 + t];
          acc[i] = fdot2f(a, wk[t], acc[i]);
        }
      }
    }
  }
  #pragma unroll
  for(int i = 0; i < 8; i++) val[i] = gelu_fast(acc[i]);
}

DEVFN void store_row_h(short* dst, int h, int w0, const float* val){
  uint32 o0 = __builtin_bit_cast(uint32, __builtin_amdgcn_cvt_pkrtz(val[0], val[1]));
  uint32 o1 = __builtin_bit_cast(uint32, __builtin_amdgcn_cvt_pkrtz(val[2], val[3]));
  uint32 o2 = __builtin_bit_cast(uint32, __builtin_amdgcn_cvt_pkrtz(val[4], val[5]));
  uint32 o3 = __builtin_bit_cast(uint32, __builtin_amdgcn_cvt_pkrtz(val[6], val[7]));
  uint2 t0; t0.x = o0; t0.y = o1;
  uint2 t1; t1.x = o2; t1.y = o3;
  *(uint2*)&dst[h * SSTR + w0 + 4] = t0;
  *(uint2*)&dst[h * SSTR + w0 + 8] = t1;
}

__global__ __launch_bounds__(512, 8)
void k_dwchain(ushort_t* __restrict__ ctxb, const uint32* __restrict__ w3p,
               const uint32* __restrict__ w5p, const uint32* __restrict__ w7p,
               const float* __restrict__ gates){
  __shared__ __align__(16) short bufA[64 * SSTR];
  __shared__ __align__(16) short bufB[64 * SSTR];
  __shared__ float wred[8];
  const int tid = threadIdx.x;
  const int plane = blockIdx.x;
  const int b = plane >> 8;
  const int c = plane & 255;
  const int h  = tid >> 3;
  const int w0 = (tid & 7) * 8;
  const int nbase = h * 64 + w0;

  if(tid < 64){
    bf16x4 z = {0, 0, 0, 0};
    *(bf16x4*)&bufA[tid * SSTR] = z;  *(bf16x4*)&bufA[tid * SSTR + 68] = z;
    *(bf16x4*)&bufB[tid * SSTR] = z;  *(bf16x4*)&bufB[tid * SSTR + 68] = z;
  }
  {
    // ctxb holds fp16 from conv1: straight bit-copy into LDS (no convert)
    const uint4 iv = *(const uint4*)((const short*)ctxb + (size_t)plane * N + tid * 8);
    uint2 t0; t0.x = iv.x; t0.y = iv.y;
    uint2 t1; t1.x = iv.z; t1.y = iv.w;
    *(uint2*)&bufA[h * SSTR + w0 + 4] = t0;
    *(uint2*)&bufA[h * SSTR + w0 + 8] = t1;
  }
  __syncthreads();

  float ctxp[8];
  #pragma unroll
  for(int i = 0; i < 8; i++) ctxp[i] = 0.f;
  float val[8];

  // stage 1: dw3 A->B
  dw_stage_dot<3>(bufA, w3p + c * 6, h, w0, val);
  {
    const float* gp = gates + ((size_t)(b * 4 + 0)) * N + nbase;
    float4 ga = *(const float4*)gp, gb = *(const float4*)(gp + 4);
    ctxp[0] = fmaf(val[0], ga.x, ctxp[0]); ctxp[1] = fmaf(val[1], ga.y, ctxp[1]);
    ctxp[2] = fmaf(val[2], ga.z, ctxp[2]); ctxp[3] = fmaf(val[3], ga.w, ctxp[3]);
    ctxp[4] = fmaf(val[4], gb.x, ctxp[4]); ctxp[5] = fmaf(val[5], gb.y, ctxp[5]);
    ctxp[6] = fmaf(val[6], gb.z, ctxp[6]); ctxp[7] = fmaf(val[7], gb.w, ctxp[7]);
    store_row_h(bufB, h, w0, val);
  }
  __syncthreads();

  // stage 2: dw5 B->A
  dw_stage_dot<5>(bufB, w5p + c * 15, h, w0, val);
  {
    const float* gp = gates + ((size_t)(b * 4 + 1)) * N + nbase;
    float4 ga = *(const float4*)gp, gb = *(const float4*)(gp + 4);
    ctxp[0] = fmaf(val[0], ga.x, ctxp[0]); ctxp[1] = fmaf(val[1], ga.y, ctxp[1]);
    ctxp[2] = fmaf(val[2], ga.z, ctxp[2]); ctxp[3] = fmaf(val[3], ga.w, ctxp[3]);
    ctxp[4] = fmaf(val[4], gb.x, ctxp[4]); ctxp[5] = fmaf(val[5], gb.y, ctxp[5]);
    ctxp[6] = fmaf(val[6], gb.z, ctxp[6]); ctxp[7] = fmaf(val[7], gb.w, ctxp[7]);
    store_row_h(bufA, h, w0, val);
  }
  __syncthreads();

  // stage 3: dw7 A->regs; plane mean of gelu output
  dw_stage_dot<7>(bufA, w7p + c * 28, h, w0, val);
  float lsum = 0.f;
  {
    const float* gp = gates + ((size_t)(b * 4 + 2)) * N + nbase;
    float4 ga = *(const float4*)gp, gb = *(const float4*)(gp + 4);
    ctxp[0] = fmaf(val[0], ga.x, ctxp[0]); ctxp[1] = fmaf(val[1], ga.y, ctxp[1]);
    ctxp[2] = fmaf(val[2], ga.z, ctxp[2]); ctxp[3] = fmaf(val[3], ga.w, ctxp[3]);
    ctxp[4] = fmaf(val[4], gb.x, ctxp[4]); ctxp[5] = fmaf(val[5], gb.y, ctxp[5]);
    ctxp[6] = fmaf(val[6], gb.z, ctxp[6]); ctxp[7] = fmaf(val[7], gb.w, ctxp[7]);
    #pragma unroll
    for(int i = 0; i < 8; i++) lsum += val[i];
  }
  #pragma unroll
  for(int off = 32; off > 0; off >>= 1) lsum += __shfl_xor(lsum, off, 64);
  if((tid & 63) == 0) wred[tid >> 6] = lsum;
  __syncthreads();
  float mean = 0.f;
  #pragma unroll
  for(int i = 0; i < 8; i++) mean += wred[i];
  mean *= (1.0f / 4096.0f);

  // ctx_all = ctxp + mean*g3 -> bf16, in place (downstream reads bf16)
  {
    const float* gp = gates + ((size_t)(b * 4 + 3)) * N + nbase;
    float4 ga = *(const float4*)gp, gb = *(const float4*)(gp + 4);
    bf16x8 ov;
    ov[0] = f2bf(fmaf(mean, ga.x, ctxp[0])); ov[1] = f2bf(fmaf(mean, ga.y, ctxp[1]));
    ov[2] = f2bf(fmaf(mean, ga.z, ctxp[2])); ov[3] = f2bf(fmaf(mean, ga.w, ctxp[3]));
    ov[4] = f2bf(fmaf(mean, gb.x, ctxp[4])); ov[5] = f2bf(fmaf(mean, gb.y, ctxp[5]));
    ov[6] = f2bf(fmaf(mean, gb.z, ctxp[6])); ov[7] = f2bf(fmaf(mean, gb.w, ctxp[7]));
    *(bf16x8*)((short*)ctxb + (size_t)plane * N + nbase) = ov;
  }
}

// ---------------- logits[b,n] = sum_c kw[c]*ctxall[b,c,n] + kb (bf16 read) ----
__global__ __launch_bounds__(256)
void k_logits(const ushort_t* __restrict__ P, const float* __restrict__ key_w,
              const float* __restrict__ key_b, float* __restrict__ logits){
  __shared__ float kw[256];
  __shared__ float part[512];
  int tid = threadIdx.x;
  kw[tid] = key_w[tid];
  __syncthreads();
  int b  = blockIdx.x >> 5;
  int n0 = (blockIdx.x & 31) * 128;
  int cpart = tid >> 6, pxp = tid & 63;
  const ushort_t* pp = P + ((size_t)(b * 256 + cpart * 64)) * N + n0 + pxp * 2;
  float a0 = 0.f, a1 = 0.f;
  #pragma unroll 8
  for(int c = 0; c < 64; c++){
    unsigned u = *(const unsigned*)(pp + (size_t)c * N);
    float kwv = kw[cpart * 64 + c];
    a0 = fmaf(lo2f(u), kwv, a0);
    a1 = fmaf(hi2f(u), kwv, a1);
  }
  part[cpart * 128 + pxp * 2]     = a0;
  part[cpart * 128 + pxp * 2 + 1] = a1;
  __syncthreads();
  if(tid < 128){
    float l = part[tid] + part[128 + tid] + part[256 + tid] + part[384 + tid];
    logits[b * N + n0 + tid] = l + key_b[0];
  }
}

// ---------------- qk with integrated softmax (reads RAW logits) ------------
__global__ __launch_bounds__(256)
void k_qk(const ushort_t* __restrict__ P, const float* __restrict__ logits,
          float* __restrict__ qk){
  __shared__ float red[256];
  __shared__ float wred[4];
  const int plane = blockIdx.x, tid = threadIdx.x;
  const int b = plane >> 8;
  const int wave = tid >> 6, lane = tid & 63;
  const float2* lp = (const float2*)(logits + b * N);
  float2 l2[8];
  float m = -1e30f;
  #pragma unroll
  for(int i = 0; i < 8; i++){
    l2[i] = lp[tid + i * 256];
    m = fmaxf(m, fmaxf(l2[i].x, l2[i].y));
  }
  #pragma unroll
  for(int off = 32; off > 0; off >>= 1) m = fmaxf(m, __shfl_xor(m, off, 64));
  if(lane == 0) wred[wave] = m;
  __syncthreads();
  m = fmaxf(fmaxf(wred[0], wred[1]), fmaxf(wred[2], wred[3]));
  __syncthreads();
  float s = 0.f;
  #pragma unroll
  for(int i = 0; i < 8; i++){
    l2[i].x = __expf(l2[i].x - m);
    l2[i].y = __expf(l2[i].y - m);
    s += l2[i].x + l2[i].y;
  }
  #pragma unroll
  for(int off = 32; off > 0; off >>= 1) s += __shfl_xor(s, off, 64);
  if(lane == 0) wred[wave] = s;
  __syncthreads();
  const float stot = wred[0] + wred[1] + wred[2] + wred[3];
  const unsigned* pp = (const unsigned*)(P + (size_t)plane * N);
  float acc = 0.f;
  #pragma unroll
  for(int i = 0; i < 8; i++){
    unsigned u = pp[tid + i * 256];
    acc = fmaf(lo2f(u), l2[i].x, acc);
    acc = fmaf(hi2f(u), l2[i].y, acc);
  }
  red[tid] = acc; __syncthreads();
  for(int t = 128; t > 0; t >>= 1){
    if(tid < t) red[tid] += red[tid + t];
    __syncthreads();
  }
  if(tid == 0) qk[plane] = red[0] / stot;
}

// ---------------- final: out = f32(ctx_all) + v, v recomputed in-block -----
__global__ __launch_bounds__(256)
void k_final(float* __restrict__ out, const ushort_t* __restrict__ ctxb,
             const float* __restrict__ qkb, const float* __restrict__ v1w,
             const float* __restrict__ v1b, const float* __restrict__ lnw,
             const float* __restrict__ lnb, const float* __restrict__ v2w,
             const float* __restrict__ v2b){
  __shared__ float part[256];
  __shared__ float v1s[16];
  __shared__ float bc[1];
  const int tid  = threadIdx.x;
  const int idx8 = blockIdx.x * 256 + tid;
  const int plane = idx8 >> 9;               // uniform within block
  const int b = plane >> 8, c = plane & 255;
  const int oc = tid >> 4, ln = tid & 15;
  const float* qs = qkb + b * 256;           // 1KB, L2-hot
  float p = 0.f;
  #pragma unroll
  for(int j = 0; j < 16; j++){
    const int cc = ln + j * 16;
    p = fmaf(v1w[oc * 256 + cc], qs[cc], p);
  }
  part[tid] = p;
  __syncthreads();
  if(tid < 16){
    float s = v1b[tid];
    #pragma unroll
    for(int j = 0; j < 16; j++) s += part[tid * 16 + j];
    v1s[tid] = s;
  }
  __syncthreads();
  if(tid == 0){
    float mu = 0.f;
    #pragma unroll
    for(int i = 0; i < 16; i++) mu += v1s[i];
    mu *= (1.f / 16.f);
    float var = 0.f;
    #pragma unroll
    for(int i = 0; i < 16; i++){ float d = v1s[i] - mu; var += d * d; }
    var *= (1.f / 16.f);
    const float rs = rsqrtf(var + 1e-5f);
    float o = v2b[c];
    #pragma unroll
    for(int i = 0; i < 16; i++){
      float vv = (v1s[i] - mu) * rs * lnw[i] + lnb[i];
      o = fmaf(v2w[c * 16 + i], fmaxf(vv, 0.f), o);
    }
    bc[0] = o;
  }
  __syncthreads();
  const float vv = bc[0];
  const int off = (idx8 & 511) * 8;
  bf16x8 v = *(const bf16x8*)((const short*)ctxb + (size_t)plane * N + off);
  float4 o0, o1;
  o0.x = bf2f((ushort_t)v[0]) + vv; o0.y = bf2f((ushort_t)v[1]) + vv;
  o0.z = bf2f((ushort_t)v[2]) + vv; o0.w = bf2f((ushort_t)v[3]) + vv;
  o1.x = bf2f((ushort_t)v[4]) + vv; o1.y = bf2f((ushort_t)v[5]) + vv;
  o1.z = bf2f((ushort_t)v[6]) + vv; o1.w = bf2f((ushort_t)v[7]) + vv;
  float* op = out + (size_t)plane * N + off;
  *(float4*)op = o0;
  *(float4*)(op + 4) = o1;
}

extern "C" void kernel_launch(void* const* d_in, const int* in_sizes, int n_in,
                              void* d_out, int out_size, void* d_ws, size_t ws_size,
                              hipStream_t stream){
  const float* x      = (const float*)d_in[0];
  const float* conv_w = (const float*)d_in[1];
  const float* conv_b = (const float*)d_in[2];
  const float* fw3    = (const float*)d_in[3];
  const float* fw5    = (const float*)d_in[4];
  const float* fw7    = (const float*)d_in[5];
  const float* key_w  = (const float*)d_in[6];
  const float* key_b  = (const float*)d_in[7];
  const float* v1_w   = (const float*)d_in[8];
  const float* v1_b   = (const float*)d_in[9];
  const float* ln_w   = (const float*)d_in[10];
  const float* ln_b   = (const float*)d_in[11];
  const float* v2_w   = (const float*)d_in[12];
  const float* v2_b   = (const float*)d_in[13];
  float* out = (float*)d_out;

  const size_t PL = (size_t)B * C * N;     // 16,777,216 elements
  char* p = (char*)d_ws;
  ushort_t* ctxb = (ushort_t*)p;  p += PL * sizeof(ushort_t);          // 32 MB
  float* gates   = (float*)p;     p += (size_t)B * 4 * N * sizeof(float);
  float* kbuf    = (float*)p;     p += (size_t)B * N * sizeof(float);
  float* qkb     = (float*)p;     p += (size_t)B * C * sizeof(float);
  ushort_t* wbf  = (ushort_t*)p;  p += (size_t)320 * 256 * sizeof(ushort_t);
  uint32* w3p    = (uint32*)p;    p += (size_t)256 * 6 * sizeof(uint32);
  uint32* w5p    = (uint32*)p;    p += (size_t)256 * 15 * sizeof(uint32);
  uint32* w7p    = (uint32*)p;

  // 0. weight pre-convert only (x transpose pass deleted)
  k_wbf<<<321, 256, 0, stream>>>(conv_w, wbf, fw3, fw5, fw7, w3p, w5p, w7p);
  // 1. conv1x1 via bf16 MFMA; X staged f32 via global_load_lds + LDS repack
  k_conv1_mfma<<<1024, 512, 0, stream>>>(x, wbf, conv_w, conv_b, ctxb, gates);
  // 2. fused dw3/dw5/dw7 chain (fp16 + v_dot2) -> ctxb overwritten bf16 ctx_all
  k_dwchain<<<B * C, 512, 0, stream>>>(ctxb, w3p, w5p, w7p, gates);
  // 3. raw logits (reads bf16 ctx_all)
  k_logits<<<512, 256, 0, stream>>>(ctxb, key_w, key_b, kbuf);
  // 4. qk with integrated per-block softmax (reads raw logits)
  k_qk<<<B * C, 256, 0, stream>>>(ctxb, kbuf, qkb);
  // 5. final: out = f32(ctx_all) + v recomputed in-block from qkb
  k_final<<<8192, 256, 0, stream>>>(out, ctxb, qkb, v1_w, v1_b, ln_w, ln_b,
                                    v2_w, v2_b);
}